// Round 3
// baseline (339.349 us; speedup 1.0000x reference)
//
#include <hip/hip_runtime.h>
#include <cstddef>
#include <cstdint>

namespace {
constexpr int kB   = 8;
constexpr int kT   = 2048;   // Tv == Ta
constexpr int kD   = 256;
constexpr int kK   = 8;      // num_neighbors (fixed by problem)
constexpr int kM   = kB * kT;
constexpr int kNCH = 32;     // s-chunks for gather partials
constexpr int kCap = 1 << 20;  // survivor-record capacity (expected ~1e3)
constexpr float kMinNormalF = 1.17549435e-38f;  // 2^-126: fp32 exp flush boundary
}

typedef __attribute__((ext_vector_type(8)))  __bf16 bf16x8;
typedef __attribute__((ext_vector_type(16))) float  f32x16;

__device__ inline unsigned short f2bf_rne(float x) {
  unsigned u = __float_as_uint(x);
  unsigned r = (u + 0x7FFFu + ((u >> 16) & 1u)) >> 16;
  return (unsigned short)r;
}

// ---- Kernel 1: C[M,256] = X[M,256] @ W[256,256] fp32; also emit bf16 copy --
__global__ __launch_bounds__(256) void gemm256(const float* __restrict__ X,
                                               const float* __restrict__ W,
                                               float* __restrict__ C,
                                               unsigned short* __restrict__ Cb) {
  __shared__ float Xs[64][33];
  __shared__ float Ws[32][64];
  const int r0 = blockIdx.x * 64;
  const int c0 = blockIdx.y * 64;
  const int tid = threadIdx.x;
  const int cg = tid & 15;
  const int rg = tid >> 4;
  float acc[4][4] = {};
  for (int k0 = 0; k0 < kD; k0 += 32) {
#pragma unroll
    for (int l = tid; l < 512; l += 256) {
      const int r = l >> 3, c4 = (l & 7) << 2;
      const float4 v = *reinterpret_cast<const float4*>(X + (size_t)(r0 + r) * kD + k0 + c4);
      Xs[r][c4 + 0] = v.x; Xs[r][c4 + 1] = v.y; Xs[r][c4 + 2] = v.z; Xs[r][c4 + 3] = v.w;
    }
#pragma unroll
    for (int l = tid; l < 512; l += 256) {
      const int kr = l >> 4, c4 = (l & 15) << 2;
      *reinterpret_cast<float4*>(&Ws[kr][c4]) =
          *reinterpret_cast<const float4*>(W + (size_t)(k0 + kr) * kD + c0 + c4);
    }
    __syncthreads();
#pragma unroll
    for (int kk = 0; kk < 32; ++kk) {
      float xv[4], wv[4];
#pragma unroll
      for (int a = 0; a < 4; ++a) xv[a] = Xs[rg * 4 + a][kk];
#pragma unroll
      for (int c = 0; c < 4; ++c) wv[c] = Ws[kk][cg * 4 + c];
#pragma unroll
      for (int a = 0; a < 4; ++a)
#pragma unroll
        for (int c = 0; c < 4; ++c) acc[a][c] = fmaf(xv[a], wv[c], acc[a][c]);
    }
    __syncthreads();
  }
#pragma unroll
  for (int a = 0; a < 4; ++a) {
    const size_t off = (size_t)(r0 + rg * 4 + a) * kD + c0 + cg * 4;
    float4 o = make_float4(acc[a][0], acc[a][1], acc[a][2], acc[a][3]);
    *reinterpret_cast<float4*>(C + off) = o;
    ushort4 ob;
    ob.x = f2bf_rne(acc[a][0]); ob.y = f2bf_rne(acc[a][1]);
    ob.z = f2bf_rne(acc[a][2]); ob.w = f2bf_rne(acc[a][3]);
    *reinterpret_cast<ushort4*>(Cb + off) = ob;
  }
}

// ---- Kernel 1b: row squared norms from fp32 vm/am --------------------------
__global__ __launch_bounds__(256) void rownorms(const float* __restrict__ vm,
                                                const float* __restrict__ am,
                                                float* __restrict__ vn2,
                                                float* __restrict__ an2) {
  const int wave = threadIdx.x >> 6, lane = threadIdx.x & 63;
  const int row = blockIdx.x * 4 + wave;
  const float* src = blockIdx.y ? am : vm;
  float* dst = blockIdx.y ? an2 : vn2;
  const float4 v = *reinterpret_cast<const float4*>(src + (size_t)row * kD + lane * 4);
  float s = v.x * v.x + v.y * v.y + v.z * v.z + v.w * v.w;
#pragma unroll
  for (int off = 32; off; off >>= 1) s += __shfl_xor(s, off, 64);
  if (lane == 0) dst[row] = s;
}

// ---- Kernel 2a: distance keys via bf16 MFMA; append rare survivors ---------
// Key semantics identical to rounds 1-2 (dist<88 guard, flush below 2^-126).
// ~3e-5 of entries survive -> append {key,(b,s,t)} records instead of storing
// the 134MB dense key matrix.
__global__ __launch_bounds__(256) void keys_mfma(const unsigned short* __restrict__ vmb,
                                                 const unsigned short* __restrict__ amb,
                                                 const float* __restrict__ vn2,
                                                 const float* __restrict__ an2,
                                                 unsigned* __restrict__ counter,
                                                 uint2* __restrict__ recs) {
  __shared__ unsigned short vmS[64 * 132];
  __shared__ unsigned short amS[64 * 132];
  const int b = blockIdx.z;
  const int t0 = blockIdx.x * 64;
  const int s0 = blockIdx.y * 64;
  const int tid = threadIdx.x;
  const int wave = tid >> 6, lane = tid & 63;
  const int wt = wave & 1, ws = wave >> 1;
  const int half = lane >> 5, ln = lane & 31;
  const unsigned short* vbase = vmb + ((size_t)b * kT + t0) * kD;
  const unsigned short* abase = amb + ((size_t)b * kT + s0) * kD;

  f32x16 acc;
#pragma unroll
  for (int i = 0; i < 16; ++i) acc[i] = 0.0f;

  union Frag { uint2 u2[2]; bf16x8 v; };

  for (int k0 = 0; k0 < kD; k0 += 128) {
#pragma unroll
    for (int i = 0; i < 4; ++i) {
      const int j = i * 256 + tid;
      const int row = j >> 4, c16 = j & 15;
      const uint4 v = *reinterpret_cast<const uint4*>(vbase + (size_t)row * kD + k0 + c16 * 8);
      uint2* dv = reinterpret_cast<uint2*>(vmS + row * 132 + c16 * 8);
      dv[0] = make_uint2(v.x, v.y); dv[1] = make_uint2(v.z, v.w);
      const uint4 a = *reinterpret_cast<const uint4*>(abase + (size_t)row * kD + k0 + c16 * 8);
      uint2* da = reinterpret_cast<uint2*>(amS + row * 132 + c16 * 8);
      da[0] = make_uint2(a.x, a.y); da[1] = make_uint2(a.z, a.w);
    }
    __syncthreads();
#pragma unroll
    for (int kk = 0; kk < 8; ++kk) {
      Frag fa, fb;
      const uint2* pa = reinterpret_cast<const uint2*>(vmS + (wt * 32 + ln) * 132 + kk * 16 + half * 8);
      fa.u2[0] = pa[0]; fa.u2[1] = pa[1];
      const uint2* pb = reinterpret_cast<const uint2*>(amS + (ws * 32 + ln) * 132 + kk * 16 + half * 8);
      fb.u2[0] = pb[0]; fb.u2[1] = pb[1];
      acc = __builtin_amdgcn_mfma_f32_32x32x16_bf16(fa.v, fb.v, acc, 0, 0, 0);
    }
    __syncthreads();
  }

  // epilogue: C/D layout col(s)=lane&31, row(t)=(reg&3)+8*(reg>>2)+4*(lane>>5)
  const int s = s0 + ws * 32 + ln;
  const float a2 = an2[(size_t)b * kT + s];
  const float* v2p = vn2 + (size_t)b * kT + t0 + wt * 32;
#pragma unroll
  for (int g = 0; g < 4; ++g) {
    const float4 v2 = *reinterpret_cast<const float4*>(v2p + g * 8 + half * 4);
    const float v2a[4] = {v2.x, v2.y, v2.z, v2.w};
#pragma unroll
    for (int j = 0; j < 4; ++j) {
      const float dot = acc[4 * g + j];
      const float sq = fmaxf(v2a[j] + a2 - 2.0f * dot, 0.0f);
      const float dist = sqrtf(sq);
      if (dist < 88.0f) {  // ~3e-5 of entries; rest of wave skips via exec mask
        const float e = expf(-dist);
        if (e >= kMinNormalF) {
          const int t = t0 + wt * 32 + g * 8 + half * 4 + j;
          const unsigned pos = ((unsigned)b << 22) | ((unsigned)s << 11) | (unsigned)t;
          const unsigned idx = atomicAdd(counter, 1u);
          if (idx < (unsigned)kCap) recs[idx] = make_uint2(__float_as_uint(e), pos);
        }
      }
    }
  }
}

// ---- Kernel 2b: per-(b,s) top-8 from the sparse survivor list --------------
// Survivors (key>0) beat the all-zero tail; zero-tail ties fill with ascending
// indices (lax.top_k stability). One thread per column.
__global__ __launch_bounds__(256) void finalize_topk(const unsigned* __restrict__ counter,
                                                     const uint2* __restrict__ recs,
                                                     int* __restrict__ idxOut) {
  __shared__ uint2 buf[1024];
  const int c = blockIdx.x * 256 + threadIdx.x;  // (b<<11)|s
  unsigned K[8];
  int T[8];
#pragma unroll
  for (int i = 0; i < 8; ++i) { K[i] = 0u; T[i] = 0x7FFFFFFF; }
  int n = (int)*counter;
  if (n > kCap) n = kCap;
  for (int base = 0; base < n; base += 1024) {
    const int m = min(1024, n - base);
    __syncthreads();
    for (int i = threadIdx.x; i < m; i += 256) buf[i] = recs[base + i];
    __syncthreads();
    for (int i = 0; i < m; ++i) {
      const uint2 r = buf[i];
      if ((int)(r.y >> 11) == c) {       // rare: ~1e3 records over 16384 cols
        const unsigned kx = r.x;
        const int tx = (int)(r.y & 2047u);
        if (kx > K[7] || (kx == K[7] && tx < T[7])) {
          K[7] = kx; T[7] = tx;
#pragma unroll
          for (int q = 7; q >= 1; --q) {
            const bool sw = (K[q] > K[q - 1]) || (K[q] == K[q - 1] && T[q] < T[q - 1]);
            if (sw) {
              const unsigned tk = K[q]; K[q] = K[q - 1]; K[q - 1] = tk;
              const int tt = T[q];      T[q] = T[q - 1]; T[q - 1] = tt;
            }
          }
        }
      }
    }
  }
  int mcnt = 0;
#pragma unroll
  for (int i = 0; i < 8; ++i) if (K[i] > 0u) mcnt++;
  int outv[8];
#pragma unroll
  for (int i = 0; i < 8; ++i) outv[i] = T[i];
  int cand = 0;
  for (int r = mcnt; r < 8; ++r) {
    bool taken = true;
    while (taken) {
      taken = false;
#pragma unroll
      for (int q = 0; q < 8; ++q)
        if (q < mcnt && T[q] == cand) taken = true;
      if (taken) cand++;
    }
    outv[r] = cand++;
  }
#pragma unroll
  for (int r = 0; r < 8; ++r) idxOut[(size_t)c * kK + r] = outv[r];
}

// ---- Kernel 3: partial gather-sums over s-chunks ---------------------------
__global__ __launch_bounds__(256) void gather_kernel(const float* __restrict__ visual,
                                                     const float* __restrict__ audio,
                                                     const int* __restrict__ idxBuf,
                                                     float* __restrict__ pv,
                                                     float* __restrict__ pa) {
  const int blk = blockIdx.x;        // bj * kNCH + ch
  const int ch = blk & (kNCH - 1);
  const int bj = blk / kNCH;
  const int j = bj & 7;
  const int b = bj >> 3;
  const int d = threadIdx.x;
  const int sBase = ch * (kT / kNCH);
  float accV = 0.f, accA = 0.f;
#pragma unroll 4
  for (int s = 0; s < kT / kNCH; ++s) {
    const int t = idxBuf[((size_t)b * kT + sBase + s) * kK + j];
    accV += visual[((size_t)b * kT + t) * kD + d];
    accA += audio[((size_t)b * kT + t) * kD + d];
  }
  pv[(size_t)blk * kD + d] = accV;
  pa[(size_t)blk * kD + d] = accA;
}

// ---- Kernel 4: reduce partials, divide by Ta, write both outputs -----------
__global__ __launch_bounds__(256) void reduce_kernel(const float* __restrict__ pv,
                                                     const float* __restrict__ pa,
                                                     float* __restrict__ out) {
  const int bj = blockIdx.x;
  const int d = threadIdx.x;
  float sV = 0.f, sA = 0.f;
#pragma unroll
  for (int ch = 0; ch < kNCH; ++ch) {
    sV += pv[((size_t)bj * kNCH + ch) * kD + d];
    sA += pa[((size_t)bj * kNCH + ch) * kD + d];
  }
  out[(size_t)bj * kD + d] = sV * (1.0f / kT);
  out[(size_t)kB * kK * kD + (size_t)bj * kD + d] = sA * (1.0f / kT);
}

extern "C" void kernel_launch(void* const* d_in, const int* in_sizes, int n_in,
                              void* d_out, int out_size, void* d_ws, size_t ws_size,
                              hipStream_t stream) {
  (void)in_sizes; (void)n_in; (void)out_size; (void)ws_size;
  const float* visual = (const float*)d_in[0];
  const float* audio  = (const float*)d_in[1];
  const float* Wv     = (const float*)d_in[2];
  const float* Wa     = (const float*)d_in[3];
  float* out = (float*)d_out;

  // workspace layout
  char* ws = (char*)d_ws;
  float* vm  = (float*)ws;                                  // kM*kD f32
  float* am  = vm + (size_t)kM * kD;                        // kM*kD f32
  float* vn2 = am + (size_t)kM * kD;                        // kM f32
  float* an2 = vn2 + kM;                                    // kM f32
  unsigned short* vmb = (unsigned short*)(an2 + kM);        // kM*kD bf16
  unsigned short* amb = vmb + (size_t)kM * kD;              // kM*kD bf16
  int* idxBuf = (int*)(amb + (size_t)kM * kD);              // kB*kT*kK i32
  float* pv = (float*)(idxBuf + (size_t)kB * kT * kK);      // kB*kK*kNCH*kD f32
  float* pa = pv + (size_t)kB * kK * kNCH * kD;
  unsigned* counter = (unsigned*)(pa + (size_t)kB * kK * kNCH * kD);  // 1 u32 (+pad)
  uint2* recs = (uint2*)(counter + 4);                      // kCap uint2

  hipMemsetAsync(counter, 0, sizeof(unsigned), stream);
  gemm256<<<dim3(kM / 64, kD / 64), 256, 0, stream>>>(visual, Wv, vm, vmb);
  gemm256<<<dim3(kM / 64, kD / 64), 256, 0, stream>>>(audio, Wa, am, amb);
  rownorms<<<dim3(kM / 4, 2), 256, 0, stream>>>(vm, am, vn2, an2);
  keys_mfma<<<dim3(kT / 64, kT / 64, kB), 256, 0, stream>>>(vmb, amb, vn2, an2, counter, recs);
  finalize_topk<<<dim3(kB * kT / 256), 256, 0, stream>>>(counter, recs, idxBuf);
  gather_kernel<<<dim3(kB * kK * kNCH), 256, 0, stream>>>(visual, audio, idxBuf, pv, pa);
  reduce_kernel<<<dim3(kB * kK), 256, 0, stream>>>(pv, pa, out);
}

// Round 4
// 244.308 us; speedup vs baseline: 1.3890x; 1.3890x over previous
//
#include <hip/hip_runtime.h>
#include <cstddef>
#include <cstdint>

namespace {
constexpr int kB   = 8;
constexpr int kT   = 2048;   // Tv == Ta
constexpr int kD   = 256;
constexpr int kK   = 8;      // num_neighbors (fixed by problem)
constexpr int kM   = kB * kT;
constexpr int kNCH = 32;     // s-chunks for gather partials
constexpr int kNC  = kB * kT;     // 16384 columns (b,s)
constexpr int kColCap = 64;       // bucket slots per column (mean load 0.55)
constexpr int kOvCap  = 1 << 17;  // overflow list (normally empty)
constexpr float kMinNormalF = 1.17549435e-38f;  // 2^-126: fp32 exp flush boundary
}

typedef __attribute__((ext_vector_type(8)))  __bf16 bf16x8;
typedef __attribute__((ext_vector_type(16))) float  f32x16;

__device__ inline unsigned short f2bf_rne(float x) {
  unsigned u = __float_as_uint(x);
  unsigned r = (u + 0x7FFFu + ((u >> 16) & 1u)) >> 16;
  return (unsigned short)r;
}

// ---- Kernel 1: C[M,256] = X[M,256] @ W[256,256] fp32; also emit bf16 copy --
__global__ __launch_bounds__(256) void gemm256(const float* __restrict__ X,
                                               const float* __restrict__ W,
                                               float* __restrict__ C,
                                               unsigned short* __restrict__ Cb) {
  __shared__ float Xs[64][33];
  __shared__ float Ws[32][64];
  const int r0 = blockIdx.x * 64;
  const int c0 = blockIdx.y * 64;
  const int tid = threadIdx.x;
  const int cg = tid & 15;
  const int rg = tid >> 4;
  float acc[4][4] = {};
  for (int k0 = 0; k0 < kD; k0 += 32) {
#pragma unroll
    for (int l = tid; l < 512; l += 256) {
      const int r = l >> 3, c4 = (l & 7) << 2;
      const float4 v = *reinterpret_cast<const float4*>(X + (size_t)(r0 + r) * kD + k0 + c4);
      Xs[r][c4 + 0] = v.x; Xs[r][c4 + 1] = v.y; Xs[r][c4 + 2] = v.z; Xs[r][c4 + 3] = v.w;
    }
#pragma unroll
    for (int l = tid; l < 512; l += 256) {
      const int kr = l >> 4, c4 = (l & 15) << 2;
      *reinterpret_cast<float4*>(&Ws[kr][c4]) =
          *reinterpret_cast<const float4*>(W + (size_t)(k0 + kr) * kD + c0 + c4);
    }
    __syncthreads();
#pragma unroll
    for (int kk = 0; kk < 32; ++kk) {
      float xv[4], wv[4];
#pragma unroll
      for (int a = 0; a < 4; ++a) xv[a] = Xs[rg * 4 + a][kk];
#pragma unroll
      for (int c = 0; c < 4; ++c) wv[c] = Ws[kk][cg * 4 + c];
#pragma unroll
      for (int a = 0; a < 4; ++a)
#pragma unroll
        for (int c = 0; c < 4; ++c) acc[a][c] = fmaf(xv[a], wv[c], acc[a][c]);
    }
    __syncthreads();
  }
#pragma unroll
  for (int a = 0; a < 4; ++a) {
    const size_t off = (size_t)(r0 + rg * 4 + a) * kD + c0 + cg * 4;
    float4 o = make_float4(acc[a][0], acc[a][1], acc[a][2], acc[a][3]);
    *reinterpret_cast<float4*>(C + off) = o;
    ushort4 ob;
    ob.x = f2bf_rne(acc[a][0]); ob.y = f2bf_rne(acc[a][1]);
    ob.z = f2bf_rne(acc[a][2]); ob.w = f2bf_rne(acc[a][3]);
    *reinterpret_cast<ushort4*>(Cb + off) = ob;
  }
}

// ---- Kernel 1b: row squared norms from fp32 vm/am --------------------------
__global__ __launch_bounds__(256) void rownorms(const float* __restrict__ vm,
                                                const float* __restrict__ am,
                                                float* __restrict__ vn2,
                                                float* __restrict__ an2) {
  const int wave = threadIdx.x >> 6, lane = threadIdx.x & 63;
  const int row = blockIdx.x * 4 + wave;
  const float* src = blockIdx.y ? am : vm;
  float* dst = blockIdx.y ? an2 : vn2;
  const float4 v = *reinterpret_cast<const float4*>(src + (size_t)row * kD + lane * 4);
  float s = v.x * v.x + v.y * v.y + v.z * v.z + v.w * v.w;
#pragma unroll
  for (int off = 32; off; off >>= 1) s += __shfl_xor(s, off, 64);
  if (lane == 0) dst[row] = s;
}

// ---- Kernel 2a: distance keys via bf16 MFMA; bucket survivors by column ----
// Key semantics identical to rounds 1-3 (dist<88 guard, flush below 2^-126).
// ~9e3 of 33.5M entries survive (measured r3: FETCH 72KB = n*8B); append
// {key,t} to the per-(b,s) bucket; overflow list is the correctness fallback.
__global__ __launch_bounds__(256) void keys_mfma(const unsigned short* __restrict__ vmb,
                                                 const unsigned short* __restrict__ amb,
                                                 const float* __restrict__ vn2,
                                                 const float* __restrict__ an2,
                                                 unsigned* __restrict__ colCount,
                                                 uint2* __restrict__ colRecs,
                                                 unsigned* __restrict__ ovCount,
                                                 uint2* __restrict__ ovRecs) {
  __shared__ unsigned short vmS[64 * 132];
  __shared__ unsigned short amS[64 * 132];
  const int b = blockIdx.z;
  const int t0 = blockIdx.x * 64;
  const int s0 = blockIdx.y * 64;
  const int tid = threadIdx.x;
  const int wave = tid >> 6, lane = tid & 63;
  const int wt = wave & 1, ws = wave >> 1;
  const int half = lane >> 5, ln = lane & 31;
  const unsigned short* vbase = vmb + ((size_t)b * kT + t0) * kD;
  const unsigned short* abase = amb + ((size_t)b * kT + s0) * kD;

  f32x16 acc;
#pragma unroll
  for (int i = 0; i < 16; ++i) acc[i] = 0.0f;

  union Frag { uint2 u2[2]; bf16x8 v; };

  for (int k0 = 0; k0 < kD; k0 += 128) {
#pragma unroll
    for (int i = 0; i < 4; ++i) {
      const int j = i * 256 + tid;
      const int row = j >> 4, c16 = j & 15;
      const uint4 v = *reinterpret_cast<const uint4*>(vbase + (size_t)row * kD + k0 + c16 * 8);
      uint2* dv = reinterpret_cast<uint2*>(vmS + row * 132 + c16 * 8);
      dv[0] = make_uint2(v.x, v.y); dv[1] = make_uint2(v.z, v.w);
      const uint4 a = *reinterpret_cast<const uint4*>(abase + (size_t)row * kD + k0 + c16 * 8);
      uint2* da = reinterpret_cast<uint2*>(amS + row * 132 + c16 * 8);
      da[0] = make_uint2(a.x, a.y); da[1] = make_uint2(a.z, a.w);
    }
    __syncthreads();
#pragma unroll
    for (int kk = 0; kk < 8; ++kk) {
      Frag fa, fb;
      const uint2* pa = reinterpret_cast<const uint2*>(vmS + (wt * 32 + ln) * 132 + kk * 16 + half * 8);
      fa.u2[0] = pa[0]; fa.u2[1] = pa[1];
      const uint2* pb = reinterpret_cast<const uint2*>(amS + (ws * 32 + ln) * 132 + kk * 16 + half * 8);
      fb.u2[0] = pb[0]; fb.u2[1] = pb[1];
      acc = __builtin_amdgcn_mfma_f32_32x32x16_bf16(fa.v, fb.v, acc, 0, 0, 0);
    }
    __syncthreads();
  }

  // epilogue: C/D layout col(s)=lane&31, row(t)=(reg&3)+8*(reg>>2)+4*(lane>>5)
  const int s = s0 + ws * 32 + ln;
  const float a2 = an2[(size_t)b * kT + s];
  const float* v2p = vn2 + (size_t)b * kT + t0 + wt * 32;
  const int c = (b << 11) | s;
#pragma unroll
  for (int g = 0; g < 4; ++g) {
    const float4 v2 = *reinterpret_cast<const float4*>(v2p + g * 8 + half * 4);
    const float v2a[4] = {v2.x, v2.y, v2.z, v2.w};
#pragma unroll
    for (int j = 0; j < 4; ++j) {
      const float dot = acc[4 * g + j];
      const float sq = fmaxf(v2a[j] + a2 - 2.0f * dot, 0.0f);
      const float dist = sqrtf(sq);
      if (dist < 88.0f) {  // ~3e-4 of entries; rest of wave skips via exec mask
        const float e = expf(-dist);
        if (e >= kMinNormalF) {
          const int t = t0 + wt * 32 + g * 8 + half * 4 + j;
          const unsigned slot = atomicAdd(&colCount[c], 1u);
          if (slot < (unsigned)kColCap) {
            colRecs[(size_t)c * kColCap + slot] = make_uint2(__float_as_uint(e), (unsigned)t);
          } else {
            const unsigned pos = ((unsigned)b << 22) | ((unsigned)s << 11) | (unsigned)t;
            const unsigned oi = atomicAdd(ovCount, 1u);
            if (oi < (unsigned)kOvCap) ovRecs[oi] = make_uint2(__float_as_uint(e), pos);
          }
        }
      }
    }
  }
}

// ---- Kernel 2b: per-column top-8 from its own bucket -----------------------
// Survivors (key>0) beat the all-zero tail; zero-tail ties fill with ascending
// indices (lax.top_k stability). One thread per column; typical bucket 0-2.
__global__ __launch_bounds__(256) void finalize_topk(const unsigned* __restrict__ colCount,
                                                     const uint2* __restrict__ colRecs,
                                                     const unsigned* __restrict__ ovCount,
                                                     const uint2* __restrict__ ovRecs,
                                                     int* __restrict__ idxOut) {
  const int c = blockIdx.x * 256 + threadIdx.x;  // (b<<11)|s
  unsigned K[8];
  int T[8];
#pragma unroll
  for (int i = 0; i < 8; ++i) { K[i] = 0u; T[i] = 0x7FFFFFFF; }
  const int cnt = (int)colCount[c];
  const int m = min(cnt, kColCap);
  for (int i = 0; i < m; ++i) {
    const uint2 r = colRecs[(size_t)c * kColCap + i];
    const unsigned kx = r.x;
    const int tx = (int)r.y;
    if (kx > K[7] || (kx == K[7] && tx < T[7])) {
      K[7] = kx; T[7] = tx;
#pragma unroll
      for (int q = 7; q >= 1; --q) {
        const bool sw = (K[q] > K[q - 1]) || (K[q] == K[q - 1] && T[q] < T[q - 1]);
        if (sw) {
          const unsigned tk = K[q]; K[q] = K[q - 1]; K[q - 1] = tk;
          const int tt = T[q];      T[q] = T[q - 1]; T[q - 1] = tt;
        }
      }
    }
  }
  if (cnt > kColCap) {  // correctness fallback; normally never taken
    int n = (int)*ovCount;
    if (n > kOvCap) n = kOvCap;
    for (int i = 0; i < n; ++i) {
      const uint2 r = ovRecs[i];
      if ((int)(r.y >> 11) == c) {
        const unsigned kx = r.x;
        const int tx = (int)(r.y & 2047u);
        if (kx > K[7] || (kx == K[7] && tx < T[7])) {
          K[7] = kx; T[7] = tx;
#pragma unroll
          for (int q = 7; q >= 1; --q) {
            const bool sw = (K[q] > K[q - 1]) || (K[q] == K[q - 1] && T[q] < T[q - 1]);
            if (sw) {
              const unsigned tk = K[q]; K[q] = K[q - 1]; K[q - 1] = tk;
              const int tt = T[q];      T[q] = T[q - 1]; T[q - 1] = tt;
            }
          }
        }
      }
    }
  }
  int mcnt = 0;
#pragma unroll
  for (int i = 0; i < 8; ++i) if (K[i] > 0u) mcnt++;
  int outv[8];
#pragma unroll
  for (int i = 0; i < 8; ++i) outv[i] = T[i];
  int cand = 0;
  for (int r = mcnt; r < 8; ++r) {
    bool taken = true;
    while (taken) {
      taken = false;
#pragma unroll
      for (int q = 0; q < 8; ++q)
        if (q < mcnt && T[q] == cand) taken = true;
      if (taken) cand++;
    }
    outv[r] = cand++;
  }
#pragma unroll
  for (int r = 0; r < 8; ++r) idxOut[(size_t)c * kK + r] = outv[r];
}

// ---- Kernel 3: partial gather-sums over s-chunks ---------------------------
__global__ __launch_bounds__(256) void gather_kernel(const float* __restrict__ visual,
                                                     const float* __restrict__ audio,
                                                     const int* __restrict__ idxBuf,
                                                     float* __restrict__ pv,
                                                     float* __restrict__ pa) {
  const int blk = blockIdx.x;        // bj * kNCH + ch
  const int ch = blk & (kNCH - 1);
  const int bj = blk / kNCH;
  const int j = bj & 7;
  const int b = bj >> 3;
  const int d = threadIdx.x;
  const int sBase = ch * (kT / kNCH);
  float accV = 0.f, accA = 0.f;
#pragma unroll 4
  for (int s = 0; s < kT / kNCH; ++s) {
    const int t = idxBuf[((size_t)b * kT + sBase + s) * kK + j];
    accV += visual[((size_t)b * kT + t) * kD + d];
    accA += audio[((size_t)b * kT + t) * kD + d];
  }
  pv[(size_t)blk * kD + d] = accV;
  pa[(size_t)blk * kD + d] = accA;
}

// ---- Kernel 4: reduce partials, divide by Ta, write both outputs -----------
__global__ __launch_bounds__(256) void reduce_kernel(const float* __restrict__ pv,
                                                     const float* __restrict__ pa,
                                                     float* __restrict__ out) {
  const int bj = blockIdx.x;
  const int d = threadIdx.x;
  float sV = 0.f, sA = 0.f;
#pragma unroll
  for (int ch = 0; ch < kNCH; ++ch) {
    sV += pv[((size_t)bj * kNCH + ch) * kD + d];
    sA += pa[((size_t)bj * kNCH + ch) * kD + d];
  }
  out[(size_t)bj * kD + d] = sV * (1.0f / kT);
  out[(size_t)kB * kK * kD + (size_t)bj * kD + d] = sA * (1.0f / kT);
}

extern "C" void kernel_launch(void* const* d_in, const int* in_sizes, int n_in,
                              void* d_out, int out_size, void* d_ws, size_t ws_size,
                              hipStream_t stream) {
  (void)in_sizes; (void)n_in; (void)out_size; (void)ws_size;
  const float* visual = (const float*)d_in[0];
  const float* audio  = (const float*)d_in[1];
  const float* Wv     = (const float*)d_in[2];
  const float* Wa     = (const float*)d_in[3];
  float* out = (float*)d_out;

  // workspace layout (~62 MB total)
  char* ws = (char*)d_ws;
  float* vm  = (float*)ws;                                  // kM*kD f32   16MB
  float* am  = vm + (size_t)kM * kD;                        // 16MB
  float* vn2 = am + (size_t)kM * kD;                        // kM f32
  float* an2 = vn2 + kM;                                    // kM f32
  unsigned short* vmb = (unsigned short*)(an2 + kM);        // kM*kD bf16  8MB
  unsigned short* amb = vmb + (size_t)kM * kD;              // 8MB
  int* idxBuf = (int*)(amb + (size_t)kM * kD);              // kB*kT*kK i32
  float* pv = (float*)(idxBuf + (size_t)kB * kT * kK);      // 2MB
  float* pa = pv + (size_t)kB * kK * kNCH * kD;             // 2MB
  unsigned* colCount = (unsigned*)(pa + (size_t)kB * kK * kNCH * kD);  // kNC u32
  unsigned* ovCount  = colCount + kNC;                      // 1 u32 (+3 pad)
  uint2* colRecs = (uint2*)(ovCount + 4);                   // kNC*kColCap uint2 8MB
  uint2* ovRecs  = colRecs + (size_t)kNC * kColCap;         // kOvCap uint2 1MB

  hipMemsetAsync(colCount, 0, (kNC + 4) * sizeof(unsigned), stream);
  gemm256<<<dim3(kM / 64, kD / 64), 256, 0, stream>>>(visual, Wv, vm, vmb);
  gemm256<<<dim3(kM / 64, kD / 64), 256, 0, stream>>>(audio, Wa, am, amb);
  rownorms<<<dim3(kM / 4, 2), 256, 0, stream>>>(vm, am, vn2, an2);
  keys_mfma<<<dim3(kT / 64, kT / 64, kB), 256, 0, stream>>>(vmb, amb, vn2, an2,
                                                            colCount, colRecs, ovCount, ovRecs);
  finalize_topk<<<dim3(kNC / 256), 256, 0, stream>>>(colCount, colRecs, ovCount, ovRecs, idxBuf);
  gather_kernel<<<dim3(kB * kK * kNCH), 256, 0, stream>>>(visual, audio, idxBuf, pv, pa);
  reduce_kernel<<<dim3(kB * kK), 256, 0, stream>>>(pv, pa, out);
}

// Round 5
// 208.543 us; speedup vs baseline: 1.6272x; 1.1715x over previous
//
#include <hip/hip_runtime.h>
#include <cstddef>
#include <cstdint>

namespace {
constexpr int kB   = 8;
constexpr int kT   = 2048;   // Tv == Ta
constexpr int kD   = 256;
constexpr int kK   = 8;      // num_neighbors (fixed by problem)
constexpr int kM   = kB * kT;
constexpr int kNCH = 32;     // s-chunks for gather partials
constexpr int kNC  = kB * kT;     // 16384 columns (b,s)
constexpr int kColCap = 64;       // bucket slots per column (mean load ~0.55)
constexpr int kOvCap  = 1 << 17;  // overflow list (normally empty)
constexpr float kMinNormalF = 1.17549435e-38f;  // 2^-126: fp32 exp flush boundary
}

typedef __attribute__((ext_vector_type(8)))  __bf16 bf16x8;
typedef __attribute__((ext_vector_type(16))) float  f32x16;

__device__ inline unsigned short f2bf_rne(float x) {
  unsigned u = __float_as_uint(x);
  unsigned r = (u + 0x7FFFu + ((u >> 16) & 1u)) >> 16;
  return (unsigned short)r;
}
__device__ inline float bf2f(unsigned short h) {
  return __uint_as_float((unsigned)h << 16);
}

// ---- Kernel 0a: cast fp32 features -> bf16 (RNE), 8 elems/thread -----------
__global__ __launch_bounds__(256) void cast_bf16(const float* __restrict__ src,
                                                 unsigned short* __restrict__ dst) {
  const size_t i = ((size_t)blockIdx.x * 256 + threadIdx.x) * 8;
  const float4 a = *reinterpret_cast<const float4*>(src + i);
  const float4 b = *reinterpret_cast<const float4*>(src + i + 4);
  ushort4 lo, hi;
  lo.x = f2bf_rne(a.x); lo.y = f2bf_rne(a.y); lo.z = f2bf_rne(a.z); lo.w = f2bf_rne(a.w);
  hi.x = f2bf_rne(b.x); hi.y = f2bf_rne(b.y); hi.z = f2bf_rne(b.z); hi.w = f2bf_rne(b.w);
  *reinterpret_cast<ushort4*>(dst + i) = lo;
  *reinterpret_cast<ushort4*>(dst + i + 4) = hi;
}

// ---- Kernel 0b: WT[c][k] = bf16(W[k][c]) (both weight mats via z) ----------
__global__ __launch_bounds__(256) void transposeW(const float* __restrict__ W,
                                                  unsigned short* __restrict__ WT) {
  __shared__ float tile[32][33];
  const int k0 = blockIdx.y * 32, c0 = blockIdx.x * 32;
  const int tx = threadIdx.x & 31, ty = threadIdx.x >> 5;  // 32 x 8
#pragma unroll
  for (int i = 0; i < 4; ++i)
    tile[ty + i * 8][tx] = W[(size_t)(k0 + ty + i * 8) * kD + c0 + tx];
  __syncthreads();
#pragma unroll
  for (int i = 0; i < 4; ++i)
    WT[(size_t)(c0 + ty + i * 8) * kD + k0 + tx] = f2bf_rne(tile[tx][ty + i * 8]);
}

// ---- Kernel 1: Cb[M,256] = bf16( Xb @ WTb^T ) via 32x32x16 MFMA ------------
// 128x64 block tile, 4 waves (32 rows each x 2 col-halves). K staged in LDS
// chunks of 64, row stride 68 shorts (136B -> 2-way bank alias: free).
__global__ __launch_bounds__(256) void gemm_mfma(const unsigned short* __restrict__ Xb,
                                                 const unsigned short* __restrict__ WTb,
                                                 unsigned short* __restrict__ Cb) {
  __shared__ unsigned short Xs[128 * 68];
  __shared__ unsigned short Ws[64 * 68];
  const int r0 = blockIdx.x * 128;
  const int c0 = blockIdx.y * 64;
  const int tid = threadIdx.x;
  const int w = tid >> 6, lane = tid & 63;
  const int half = lane >> 5, ln = lane & 31;

  f32x16 acc[2];
#pragma unroll
  for (int j = 0; j < 2; ++j)
#pragma unroll
    for (int i = 0; i < 16; ++i) acc[j][i] = 0.0f;

  union Frag { uint2 u2[2]; bf16x8 v; };

  for (int k0 = 0; k0 < kD; k0 += 64) {
#pragma unroll
    for (int i = 0; i < 4; ++i) {           // stage X: 128 rows x 64 shorts
      const int j = i * 256 + tid;
      const int row = j >> 3, c8 = (j & 7) * 8;
      const uint4 v = *reinterpret_cast<const uint4*>(Xb + (size_t)(r0 + row) * kD + k0 + c8);
      *reinterpret_cast<uint4*>(Xs + row * 68 + c8) = v;
    }
#pragma unroll
    for (int i = 0; i < 2; ++i) {           // stage WT: 64 rows x 64 shorts
      const int j = i * 256 + tid;
      const int row = j >> 3, c8 = (j & 7) * 8;
      const uint4 v = *reinterpret_cast<const uint4*>(WTb + (size_t)(c0 + row) * kD + k0 + c8);
      *reinterpret_cast<uint4*>(Ws + row * 68 + c8) = v;
    }
    __syncthreads();
#pragma unroll
    for (int kk = 0; kk < 4; ++kk) {
      Frag fa, fb0, fb1;
      const uint2* pa = reinterpret_cast<const uint2*>(Xs + (w * 32 + ln) * 68 + kk * 16 + half * 8);
      fa.u2[0] = pa[0]; fa.u2[1] = pa[1];
      const uint2* p0 = reinterpret_cast<const uint2*>(Ws + ln * 68 + kk * 16 + half * 8);
      fb0.u2[0] = p0[0]; fb0.u2[1] = p0[1];
      const uint2* p1 = reinterpret_cast<const uint2*>(Ws + (32 + ln) * 68 + kk * 16 + half * 8);
      fb1.u2[0] = p1[0]; fb1.u2[1] = p1[1];
      acc[0] = __builtin_amdgcn_mfma_f32_32x32x16_bf16(fa.v, fb0.v, acc[0], 0, 0, 0);
      acc[1] = __builtin_amdgcn_mfma_f32_32x32x16_bf16(fa.v, fb1.v, acc[1], 0, 0, 0);
    }
    __syncthreads();
  }
  // C/D layout: col = c0 + jj*32 + ln; row = r0 + w*32 + (r&3)+8*(r>>2)+4*half
#pragma unroll
  for (int jj = 0; jj < 2; ++jj) {
    const int col = c0 + jj * 32 + ln;
#pragma unroll
    for (int r = 0; r < 16; ++r) {
      const int row = r0 + w * 32 + (r & 3) + 8 * (r >> 2) + 4 * half;
      Cb[(size_t)row * kD + col] = f2bf_rne(acc[jj][r]);
    }
  }
}

// ---- Kernel 1b: row squared norms from the bf16 matrices -------------------
// Norms of the SAME rounded vectors the MFMA dot uses -> sq == ||v-a||^2 of
// rounded vectors, consistent selection.
__global__ __launch_bounds__(256) void rownorms(const unsigned short* __restrict__ vmb,
                                                const unsigned short* __restrict__ amb,
                                                float* __restrict__ vn2,
                                                float* __restrict__ an2) {
  const int wave = threadIdx.x >> 6, lane = threadIdx.x & 63;
  const int row = blockIdx.x * 4 + wave;
  const unsigned short* src = blockIdx.y ? amb : vmb;
  float* dst = blockIdx.y ? an2 : vn2;
  const ushort4 v = *reinterpret_cast<const ushort4*>(src + (size_t)row * kD + lane * 4);
  const float x = bf2f(v.x), y = bf2f(v.y), z = bf2f(v.z), ww = bf2f(v.w);
  float s = x * x + y * y + z * z + ww * ww;
#pragma unroll
  for (int off = 32; off; off >>= 1) s += __shfl_xor(s, off, 64);
  if (lane == 0) dst[row] = s;
}

// ---- Kernel 2a: distance keys via bf16 MFMA, 128x128 tile; bucket survivors
// Key semantics identical to rounds 1-4 (dist<88 guard, flush below 2^-126).
__global__ __launch_bounds__(256) void keys_mfma(const unsigned short* __restrict__ vmb,
                                                 const unsigned short* __restrict__ amb,
                                                 const float* __restrict__ vn2,
                                                 const float* __restrict__ an2,
                                                 unsigned* __restrict__ colCount,
                                                 uint2* __restrict__ colRecs,
                                                 unsigned* __restrict__ ovCount,
                                                 uint2* __restrict__ ovRecs) {
  __shared__ unsigned short vmS[128 * 68];
  __shared__ unsigned short amS[128 * 68];
  const int b = blockIdx.z;
  const int t0 = blockIdx.x * 128;
  const int s0 = blockIdx.y * 128;
  const int tid = threadIdx.x;
  const int wave = tid >> 6, lane = tid & 63;
  const int wt = wave & 1, wsi = wave >> 1;
  const int half = lane >> 5, ln = lane & 31;
  const unsigned short* vbase = vmb + ((size_t)b * kT + t0) * kD;
  const unsigned short* abase = amb + ((size_t)b * kT + s0) * kD;

  f32x16 acc[2][2];
#pragma unroll
  for (int i = 0; i < 2; ++i)
#pragma unroll
    for (int j = 0; j < 2; ++j)
#pragma unroll
      for (int q = 0; q < 16; ++q) acc[i][j][q] = 0.0f;

  union Frag { uint2 u2[2]; bf16x8 v; };

  for (int k0 = 0; k0 < kD; k0 += 64) {
#pragma unroll
    for (int i = 0; i < 4; ++i) {           // stage vm: 128 rows x 64 shorts
      const int j = i * 256 + tid;
      const int row = j >> 3, c8 = (j & 7) * 8;
      const uint4 v = *reinterpret_cast<const uint4*>(vbase + (size_t)row * kD + k0 + c8);
      *reinterpret_cast<uint4*>(vmS + row * 68 + c8) = v;
      const uint4 a = *reinterpret_cast<const uint4*>(abase + (size_t)row * kD + k0 + c8);
      *reinterpret_cast<uint4*>(amS + row * 68 + c8) = a;
    }
    __syncthreads();
#pragma unroll
    for (int kk = 0; kk < 4; ++kk) {
      Frag fa[2], fb[2];
#pragma unroll
      for (int i = 0; i < 2; ++i) {
        const uint2* pa = reinterpret_cast<const uint2*>(vmS + (wt * 64 + i * 32 + ln) * 68 + kk * 16 + half * 8);
        fa[i].u2[0] = pa[0]; fa[i].u2[1] = pa[1];
        const uint2* pb = reinterpret_cast<const uint2*>(amS + (wsi * 64 + i * 32 + ln) * 68 + kk * 16 + half * 8);
        fb[i].u2[0] = pb[0]; fb[i].u2[1] = pb[1];
      }
#pragma unroll
      for (int i = 0; i < 2; ++i)
#pragma unroll
        for (int j = 0; j < 2; ++j)
          acc[i][j] = __builtin_amdgcn_mfma_f32_32x32x16_bf16(fa[i].v, fb[j].v, acc[i][j], 0, 0, 0);
    }
    __syncthreads();
  }

  // epilogue: per subtile, col(s)=lane&31, row(t)=(reg&3)+8*(reg>>2)+4*half
#pragma unroll
  for (int j = 0; j < 2; ++j) {
    const int s = s0 + wsi * 64 + j * 32 + ln;
    const float a2 = an2[(size_t)b * kT + s];
    const int c = (b << 11) | s;
#pragma unroll
    for (int i = 0; i < 2; ++i) {
      const int tb = t0 + wt * 64 + i * 32;
      const float* v2p = vn2 + (size_t)b * kT + tb;
#pragma unroll
      for (int g = 0; g < 4; ++g) {
        const float4 v2 = *reinterpret_cast<const float4*>(v2p + g * 8 + half * 4);
        const float v2a[4] = {v2.x, v2.y, v2.z, v2.w};
#pragma unroll
        for (int q = 0; q < 4; ++q) {
          const float dot = acc[i][j][4 * g + q];
          const float sq = fmaxf(v2a[q] + a2 - 2.0f * dot, 0.0f);
          const float dist = sqrtf(sq);
          if (dist < 88.0f) {  // ~3e-4 of entries; rest skip via exec mask
            const float e = expf(-dist);
            if (e >= kMinNormalF) {
              const int t = tb + g * 8 + half * 4 + q;
              const unsigned slot = atomicAdd(&colCount[c], 1u);
              if (slot < (unsigned)kColCap) {
                colRecs[(size_t)c * kColCap + slot] = make_uint2(__float_as_uint(e), (unsigned)t);
              } else {
                const unsigned pos = ((unsigned)b << 22) | ((unsigned)s << 11) | (unsigned)t;
                const unsigned oi = atomicAdd(ovCount, 1u);
                if (oi < (unsigned)kOvCap) ovRecs[oi] = make_uint2(__float_as_uint(e), pos);
              }
            }
          }
        }
      }
    }
  }
}

// ---- Kernel 2b: per-column top-8 from its own bucket -----------------------
__global__ __launch_bounds__(256) void finalize_topk(const unsigned* __restrict__ colCount,
                                                     const uint2* __restrict__ colRecs,
                                                     const unsigned* __restrict__ ovCount,
                                                     const uint2* __restrict__ ovRecs,
                                                     int* __restrict__ idxOut) {
  const int c = blockIdx.x * 256 + threadIdx.x;  // (b<<11)|s
  unsigned K[8];
  int T[8];
#pragma unroll
  for (int i = 0; i < 8; ++i) { K[i] = 0u; T[i] = 0x7FFFFFFF; }
  const int cnt = (int)colCount[c];
  const int m = min(cnt, kColCap);
  for (int i = 0; i < m; ++i) {
    const uint2 r = colRecs[(size_t)c * kColCap + i];
    const unsigned kx = r.x;
    const int tx = (int)r.y;
    if (kx > K[7] || (kx == K[7] && tx < T[7])) {
      K[7] = kx; T[7] = tx;
#pragma unroll
      for (int q = 7; q >= 1; --q) {
        const bool sw = (K[q] > K[q - 1]) || (K[q] == K[q - 1] && T[q] < T[q - 1]);
        if (sw) {
          const unsigned tk = K[q]; K[q] = K[q - 1]; K[q - 1] = tk;
          const int tt = T[q];      T[q] = T[q - 1]; T[q - 1] = tt;
        }
      }
    }
  }
  if (cnt > kColCap) {  // correctness fallback; normally never taken
    int n = (int)*ovCount;
    if (n > kOvCap) n = kOvCap;
    for (int i = 0; i < n; ++i) {
      const uint2 r = ovRecs[i];
      if ((int)(r.y >> 11) == c) {
        const unsigned kx = r.x;
        const int tx = (int)(r.y & 2047u);
        if (kx > K[7] || (kx == K[7] && tx < T[7])) {
          K[7] = kx; T[7] = tx;
#pragma unroll
          for (int q = 7; q >= 1; --q) {
            const bool sw = (K[q] > K[q - 1]) || (K[q] == K[q - 1] && T[q] < T[q - 1]);
            if (sw) {
              const unsigned tk = K[q]; K[q] = K[q - 1]; K[q - 1] = tk;
              const int tt = T[q];      T[q] = T[q - 1]; T[q - 1] = tt;
            }
          }
        }
      }
    }
  }
  int mcnt = 0;
#pragma unroll
  for (int i = 0; i < 8; ++i) if (K[i] > 0u) mcnt++;
  int outv[8];
#pragma unroll
  for (int i = 0; i < 8; ++i) outv[i] = T[i];
  int cand = 0;
  for (int r = mcnt; r < 8; ++r) {
    bool taken = true;
    while (taken) {
      taken = false;
#pragma unroll
      for (int q = 0; q < 8; ++q)
        if (q < mcnt && T[q] == cand) taken = true;
      if (taken) cand++;
    }
    outv[r] = cand++;
  }
#pragma unroll
  for (int r = 0; r < 8; ++r) idxOut[(size_t)c * kK + r] = outv[r];
}

// ---- Kernel 3: partial gather-sums over s-chunks ---------------------------
__global__ __launch_bounds__(256) void gather_kernel(const float* __restrict__ visual,
                                                     const float* __restrict__ audio,
                                                     const int* __restrict__ idxBuf,
                                                     float* __restrict__ pv,
                                                     float* __restrict__ pa) {
  const int blk = blockIdx.x;        // bj * kNCH + ch
  const int ch = blk & (kNCH - 1);
  const int bj = blk / kNCH;
  const int j = bj & 7;
  const int b = bj >> 3;
  const int d = threadIdx.x;
  const int sBase = ch * (kT / kNCH);
  float accV = 0.f, accA = 0.f;
#pragma unroll 4
  for (int s = 0; s < kT / kNCH; ++s) {
    const int t = idxBuf[((size_t)b * kT + sBase + s) * kK + j];
    accV += visual[((size_t)b * kT + t) * kD + d];
    accA += audio[((size_t)b * kT + t) * kD + d];
  }
  pv[(size_t)blk * kD + d] = accV;
  pa[(size_t)blk * kD + d] = accA;
}

// ---- Kernel 4: reduce partials, divide by Ta, write both outputs -----------
__global__ __launch_bounds__(256) void reduce_kernel(const float* __restrict__ pv,
                                                     const float* __restrict__ pa,
                                                     float* __restrict__ out) {
  const int bj = blockIdx.x;
  const int d = threadIdx.x;
  float sV = 0.f, sA = 0.f;
#pragma unroll
  for (int ch = 0; ch < kNCH; ++ch) {
    sV += pv[((size_t)bj * kNCH + ch) * kD + d];
    sA += pa[((size_t)bj * kNCH + ch) * kD + d];
  }
  out[(size_t)bj * kD + d] = sV * (1.0f / kT);
  out[(size_t)kB * kK * kD + (size_t)bj * kD + d] = sA * (1.0f / kT);
}

extern "C" void kernel_launch(void* const* d_in, const int* in_sizes, int n_in,
                              void* d_out, int out_size, void* d_ws, size_t ws_size,
                              hipStream_t stream) {
  (void)in_sizes; (void)n_in; (void)out_size; (void)ws_size;
  const float* visual = (const float*)d_in[0];
  const float* audio  = (const float*)d_in[1];
  const float* Wv     = (const float*)d_in[2];
  const float* Wa     = (const float*)d_in[3];
  float* out = (float*)d_out;

  // workspace layout (~46 MB)
  char* ws = (char*)d_ws;
  unsigned short* vb  = (unsigned short*)ws;                // kM*kD bf16  8MB
  unsigned short* ab  = vb + (size_t)kM * kD;               // 8MB
  unsigned short* WvT = ab + (size_t)kM * kD;               // kD*kD bf16 128KB
  unsigned short* WaT = WvT + (size_t)kD * kD;
  unsigned short* vmb = WaT + (size_t)kD * kD;              // kM*kD bf16  8MB
  unsigned short* amb = vmb + (size_t)kM * kD;              // 8MB
  float* vn2 = (float*)(amb + (size_t)kM * kD);             // kM f32
  float* an2 = vn2 + kM;
  int* idxBuf = (int*)(an2 + kM);                           // kB*kT*kK i32
  float* pv = (float*)(idxBuf + (size_t)kB * kT * kK);      // 2MB
  float* pa = pv + (size_t)kB * kK * kNCH * kD;             // 2MB
  unsigned* colCount = (unsigned*)(pa + (size_t)kB * kK * kNCH * kD);  // kNC u32
  unsigned* ovCount  = colCount + kNC;                      // 1 u32 (+3 pad)
  uint2* colRecs = (uint2*)(ovCount + 4);                   // kNC*kColCap uint2 8MB
  uint2* ovRecs  = colRecs + (size_t)kNC * kColCap;         // kOvCap uint2 1MB

  hipMemsetAsync(colCount, 0, (kNC + 4) * sizeof(unsigned), stream);
  cast_bf16<<<dim3(kM * kD / (256 * 8)), 256, 0, stream>>>(visual, vb);
  cast_bf16<<<dim3(kM * kD / (256 * 8)), 256, 0, stream>>>(audio, ab);
  transposeW<<<dim3(kD / 32, kD / 32), 256, 0, stream>>>(Wv, WvT);
  transposeW<<<dim3(kD / 32, kD / 32), 256, 0, stream>>>(Wa, WaT);
  gemm_mfma<<<dim3(kM / 128, kD / 64), 256, 0, stream>>>(vb, WvT, vmb);
  gemm_mfma<<<dim3(kM / 128, kD / 64), 256, 0, stream>>>(ab, WaT, amb);
  rownorms<<<dim3(kM / 4, 2), 256, 0, stream>>>(vmb, amb, vn2, an2);
  keys_mfma<<<dim3(kT / 128, kT / 128, kB), 256, 0, stream>>>(vmb, amb, vn2, an2,
                                                              colCount, colRecs, ovCount, ovRecs);
  finalize_topk<<<dim3(kNC / 256), 256, 0, stream>>>(colCount, colRecs, ovCount, ovRecs, idxBuf);
  gather_kernel<<<dim3(kB * kK * kNCH), 256, 0, stream>>>(visual, audio, idxBuf, pv, pa);
  reduce_kernel<<<dim3(kB * kK), 256, 0, stream>>>(pv, pa, out);
}